// Round 10
// baseline (329.769 us; speedup 1.0000x reference)
//
#include <hip/hip_runtime.h>
#include <hip/hip_fp16.h>

// GridEncoder (instant-NGP triplane hash grid), static config:
//   D=3, L=3, C=2, base_res=128, per_level_scale=2, hashmap=2^19,
//   align_corners=False, linear interp, B=2^21.
// All levels hash-index; hmap=2^19 -> mod == & 0x7FFFF.
//
// R1: naive fp32 -> kernel 543 us, total 587 -> fixed harness overhead ~43.
// R2..R7: half2-packed table, fused gather, mixed-width x-pair loads
//     (15 req/pt = floor of this layout class). Cost model per divergent
//     lane-request ~= 1.65 cyc + 0.12 cyc/B — fits R2/R4/R5/R6/R8.
// R8: level-clustered gather (one 2 MB level table L2-resident at a time):
//     gather 128 us = 37.5 cyc/pt == model floor; FETCH 474 -> 110 MB.
//     Residue 70 us = 43 fixed + ~27 prepass dispatch/drain.
// R9: hipLaunchCooperativeKernel silently failed under graph capture
//     (output never written). R10: same fusion via PLAIN launch + manual
//     grid barrier. Co-residency by construction: 1024 blocks,
//     __launch_bounds__(256,4) => VGPR<=128, LDS=0 => 4 blocks/CU x 256 CU
//     = 1024 resident. Barrier counter in d_ws, zeroed by a capture-safe
//     hipMemsetAsync node. Gather = 2 sweeps x 4 pts/thread to stay within
//     the 128-VGPR cap (R8's footprint was 108 at PPT=4).

#define NPOINTS  2097152
#define HMASK    0x7FFFFu
#define PLANE    524288            // entries per level table
#define NTAB     (3 * PLANE)       // packed half2 entries (6 MB)
#define NQUADS   (NTAB / 4)        // 393216
#define CBLOCKS  1024
#define CTHREADS (CBLOCKS * 256)   // 262144
#define SWEEPS   2
#define PPT      4                 // points per thread per sweep (2*4*262144 = 2M)

typedef float    floatx2 __attribute__((ext_vector_type(2)));
typedef unsigned uintx2  __attribute__((ext_vector_type(2)));
typedef unsigned uintx4  __attribute__((ext_vector_type(4)));

__device__ __forceinline__ unsigned pack2(float a, float b) {
    const __half2 h2 = __halves2half2(__float2half_rn(a), __float2half_rn(b));
    return *reinterpret_cast<const unsigned*>(&h2);
}

__device__ __forceinline__ unsigned sel4(uintx4 q, unsigned o) {
    const unsigned a = (o & 1u) ? q.y : q.x;
    const unsigned b = (o & 1u) ? q.w : q.z;
    return (o & 2u) ? b : a;
}

__device__ __forceinline__ void convert_quad(
    const float* __restrict__ tp, uintx4* __restrict__ tbl4, unsigned q)
{
    const unsigned level = q >> 17;                       // 2^17 quads/level
    const unsigned i4    = (q & 131071u) << 2;
    const float* __restrict__ b = tp + level * (2u * PLANE);
    const float4 c0 = *reinterpret_cast<const float4*>(b + i4);
    const float4 c1 = *reinterpret_cast<const float4*>(b + PLANE + i4);
    uintx4 o;
    o.x = pack2(c0.x, c1.x);
    o.y = pack2(c0.y, c1.y);
    o.z = pack2(c0.z, c1.z);
    o.w = pack2(c0.w, c1.w);
    tbl4[q] = o;
}

// ---- fused: convert -> manual grid barrier -> level-clustered gather ----
__global__ __launch_bounds__(256, 4) void grid_fused_kernel(
    const float* __restrict__ triplane,
    const float* __restrict__ inputs,
    unsigned* __restrict__ tbl,
    unsigned* __restrict__ counter,   // zeroed via hipMemsetAsync each call
    floatx2* __restrict__ out)
{
    const int t = blockIdx.x * 256 + threadIdx.x;         // < CTHREADS

    // ---- phase A: convert fp32 triplane -> packed half2 table ----
    {
        uintx4* tbl4 = reinterpret_cast<uintx4*>(tbl);
        convert_quad(triplane, tbl4, (unsigned)t);
        const unsigned q2 = (unsigned)t + (unsigned)CTHREADS;
        if (q2 < (unsigned)NQUADS) convert_quad(triplane, tbl4, q2);
    }

    // ---- manual grid barrier (all 1024 blocks are co-resident) ----
    __syncthreads();                      // all threads in block done converting
    if (threadIdx.x == 0) {
        __threadfence();                  // release: table writes device-visible
        atomicAdd(counter, 1u);
        while (atomicAdd(counter, 0u) < (unsigned)CBLOCKS)
            __builtin_amdgcn_s_sleep(2);
        __threadfence();                  // acquire
    }
    __syncthreads();

    // ---- phase B: level-clustered gather, 2 sweeps x 4 pts/thread ----
    for (int sweep = 0; sweep < SWEEPS; ++sweep) {
        float x0[PPT], y0[PPT], z0[PPT];
#pragma unroll
        for (int p = 0; p < PPT; ++p) {
            const int i = t + (sweep * PPT + p) * CTHREADS;
            const float x = __builtin_nontemporal_load(&inputs[3 * i + 0]);
            const float y = __builtin_nontemporal_load(&inputs[3 * i + 1]);
            const float z = __builtin_nontemporal_load(&inputs[3 * i + 2]);
            x0[p] = (x + 1.0f) * 0.5f;
            y0[p] = (y + 1.0f) * 0.5f;
            z0[p] = (z + 1.0f) * 0.5f;
        }

        float o0[PPT], o1[PPT];
#pragma unroll
        for (int p = 0; p < PPT; ++p) { o0[p] = 0.0f; o1[p] = 0.0f; }

#pragma unroll
        for (int level = 0; level < 3; ++level) {
            const float scale = (float)((128 << level) - 1);  // 127, 255, 511
            const unsigned lvl = (unsigned)level << 19;

#pragma unroll
            for (int p = 0; p < PPT; ++p) {
                const float px = fmaf(x0[p], scale, 0.5f);
                const float py = fmaf(y0[p], scale, 0.5f);
                const float pz = fmaf(z0[p], scale, 0.5f);
                const float fx = floorf(px), fy = floorf(py), fz = floorf(pz);
                const float rx = px - fx, ry = py - fy, rz = pz - fz;
                const unsigned gx = (unsigned)fx, gy = (unsigned)fy, gz = (unsigned)fz;

                const unsigned d = gx ^ (gx + 1u);            // 1,3,7,15,...
                const unsigned hy0 = gy * 2654435761u;
                const unsigned hy1 = (gy + 1u) * 2654435761u;
                const unsigned hz0 = gz * 805459861u;
                const unsigned hz1 = (gz + 1u) * 805459861u;

                unsigned P0[4];
                P0[0] = lvl | ((gx ^ hy0 ^ hz0) & HMASK);
                P0[1] = lvl | ((gx ^ hy1 ^ hz0) & HMASK);
                P0[2] = lvl | ((gx ^ hy0 ^ hz1) & HMASK);
                P0[3] = lvl | ((gx ^ hy1 ^ hz1) & HMASK);

                unsigned e0[4], e1[4];
                if (d == 1u) {
                    // partner adjacent within aligned 8B (p = 1/2)
#pragma unroll
                    for (int j = 0; j < 4; ++j) {
                        const unsigned P = P0[j];
                        const uintx2 q = *reinterpret_cast<const uintx2*>(tbl + (P & ~1u));
                        const unsigned o = P & 1u;
                        e0[j] = o ? q.y : q.x;
                        e1[j] = o ? q.x : q.y;
                    }
                } else if (d == 3u) {
                    // partner within aligned 16B quad (p = 1/4)
#pragma unroll
                    for (int j = 0; j < 4; ++j) {
                        const unsigned P = P0[j];
                        const uintx4 q = *reinterpret_cast<const uintx4*>(tbl + (P & ~3u));
                        const unsigned o = P & 3u;
                        e0[j] = sel4(q, o);
                        e1[j] = sel4(q, o ^ 3u);
                    }
                } else {
                    // distant partner: two scalar 4B loads (p = 1/4)
#pragma unroll
                    for (int j = 0; j < 4; ++j) {
                        const unsigned P = P0[j];
                        e0[j] = tbl[P];
                        e1[j] = tbl[P ^ d];
                    }
                }

                const float wx1 = rx, wx0 = 1.0f - rx;
                const float wy1 = ry, wy0 = 1.0f - ry;
                const float wz1 = rz, wz0 = 1.0f - rz;
                const float wyz[4] = { wy0 * wz0, wy1 * wz0, wy0 * wz1, wy1 * wz1 };
#pragma unroll
                for (int j = 0; j < 4; ++j) {
                    const __half2 a = *reinterpret_cast<const __half2*>(&e0[j]);
                    const __half2 b = *reinterpret_cast<const __half2*>(&e1[j]);
                    const float2 fa = __half22float2(a);
                    const float2 fb = __half22float2(b);
                    const float wA = wx0 * wyz[j], wB = wx1 * wyz[j];
                    o0[p] = fmaf(wA, fa.x, o0[p]); o1[p] = fmaf(wA, fa.y, o1[p]);
                    o0[p] = fmaf(wB, fb.x, o0[p]); o1[p] = fmaf(wB, fb.y, o1[p]);
                }
            }
            // keep resident waves on the same level -> one 2 MB level table
            // hot in L2 at a time (statistical clustering, as in R8)
            __syncthreads();
        }

#pragma unroll
        for (int p = 0; p < PPT; ++p) {
            floatx2 r; r.x = o0[p]; r.y = o1[p];
            __builtin_nontemporal_store(r, &out[t + (sweep * PPT + p) * CTHREADS]);
        }
    }
}

// ---- fallback (R1 kernel) if ws_size is too small for the packed table ----
__global__ __launch_bounds__(256) void grid_fallback_kernel(
    const float* __restrict__ triplane,
    const float* __restrict__ inputs,
    float* __restrict__ out)
{
    const int i = blockIdx.x * blockDim.x + threadIdx.x;
    if (i >= NPOINTS) return;
    const float x0 = (inputs[3 * i + 0] + 1.0f) * 0.5f;
    const float y0 = (inputs[3 * i + 1] + 1.0f) * 0.5f;
    const float z0 = (inputs[3 * i + 2] + 1.0f) * 0.5f;
    float o0 = 0.0f, o1 = 0.0f;
#pragma unroll
    for (int level = 0; level < 3; ++level) {
        const float scale = (float)((128 << level) - 1);
        const float px = fmaf(x0, scale, 0.5f);
        const float py = fmaf(y0, scale, 0.5f);
        const float pz = fmaf(z0, scale, 0.5f);
        const float fx = floorf(px), fy = floorf(py), fz = floorf(pz);
        const float rx = px - fx, ry = py - fy, rz = pz - fz;
        const unsigned gx = (unsigned)fx, gy = (unsigned)fy, gz = (unsigned)fz;
        const float* __restrict__ base = triplane + level * (2 * PLANE);
#pragma unroll
        for (int c = 0; c < 8; ++c) {
            const unsigned bx = (c >> 0) & 1, by = (c >> 1) & 1, bz = (c >> 2) & 1;
            const unsigned h = (gx + bx) ^ ((gy + by) * 2654435761u) ^ ((gz + bz) * 805459861u);
            const unsigned local = h & HMASK;
            const float w = (bx ? rx : 1.0f - rx) * (by ? ry : 1.0f - ry) * (bz ? rz : 1.0f - rz);
            o0 = fmaf(w, base[local], o0);
            o1 = fmaf(w, base[PLANE + local], o1);
        }
    }
    reinterpret_cast<float2*>(out)[i] = make_float2(o0, o1);
}

extern "C" void kernel_launch(void* const* d_in, const int* in_sizes, int n_in,
                              void* d_out, int out_size, void* d_ws, size_t ws_size,
                              hipStream_t stream) {
    const float* triplane = (const float*)d_in[0];  // 3*2*1024*512 fp32
    const float* inputs   = (const float*)d_in[1];  // B*3 fp32

    if (ws_size >= (size_t)NTAB * sizeof(unsigned) + 64) {
        unsigned* tbl = (unsigned*)d_ws;
        unsigned* counter = tbl + NTAB;             // 4 bytes past the table
        hipMemsetAsync(counter, 0, sizeof(unsigned), stream);  // capture-safe node
        grid_fused_kernel<<<CBLOCKS, 256, 0, stream>>>(
            triplane, inputs, tbl, counter, (floatx2*)d_out);
    } else {
        grid_fallback_kernel<<<NPOINTS / 256, 256, 0, stream>>>(
            triplane, inputs, (float*)d_out);
    }
}

// Round 11
// 198.525 us; speedup vs baseline: 1.6611x; 1.6611x over previous
//
#include <hip/hip_runtime.h>
#include <hip/hip_fp16.h>

// GridEncoder (instant-NGP triplane hash grid), static config:
//   D=3, L=3, C=2, base_res=128, per_level_scale=2, hashmap=2^19,
//   align_corners=False, linear interp, B=2^21.
// All levels hash-index; hmap=2^19 -> mod == & 0x7FFFF.
//
// R1: naive fp32 -> kernel 543 us, total 587 -> fixed harness overhead ~44.
// R2..R7: half2-packed table, fused gather, mixed-width x-pair loads
//     (15 req/pt = floor of this layout class). Cost model per divergent
//     lane-request ~= 1.65 cyc + 0.12 cyc/B — fits R2/R4/R5/R6/R8.
// R8 (THIS KERNEL): level-clustered gather, one 2 MB level table L2-resident
//     at a time: gather 128 us = 37.5 cyc/pt == model floor; FETCH 110 MB;
//     PPT=4 -> ~60 outstanding loads/wave == vmcnt cap. Total 198 us.
// R9: hipLaunchCooperativeKernel silently no-ops under graph capture.
// R10: fused + manual barrier: correct, but __launch_bounds__(256,4) let the
//     compiler drop to 64 VGPRs -> in-flight gather results don't fit ->
//     waitcnt serialization, MLP collapse (37.5 -> 71 cyc/pt), and residue
//     did NOT shrink (76 us vs R8's ~65). Fusion falsified both ways.
// R11: revert to R8 exactly — gather at request-cost floor + vmcnt cap +
//     L2 residency; remaining ~70 us is harness-fixed + prepass node.

#define NPOINTS  2097152
#define HMASK    0x7FFFFu
#define PLANE    524288            // entries per level table
#define NTAB     (3 * PLANE)       // packed half2 entries (6 MB)
#define GBLOCKS  2048
#define TTHREADS (GBLOCKS * 256)   // 524288
#define PPT      4                 // points per thread

typedef float    floatx2 __attribute__((ext_vector_type(2)));
typedef unsigned uintx2  __attribute__((ext_vector_type(2)));
typedef unsigned uintx4  __attribute__((ext_vector_type(4)));

__device__ __forceinline__ unsigned pack2(float a, float b) {
    const __half2 h2 = __halves2half2(__float2half_rn(a), __float2half_rn(b));
    return *reinterpret_cast<const unsigned*>(&h2);
}

// ---- prepass: tbl[level*2^19 + h] = half2(b[h], b[PLANE+h]) ----
__global__ __launch_bounds__(256) void tp_convert_kernel(
    const float* __restrict__ tp, uintx4* __restrict__ tbl)
{
    const unsigned t = blockIdx.x * 256u + threadIdx.x;   // < NTAB/4
    const unsigned level = t >> 17;                       // 2^17 quads/level
    const unsigned i4    = (t & 131071u) << 2;
    const float* __restrict__ b = tp + level * (2u * PLANE);
    const float4 c0 = *reinterpret_cast<const float4*>(b + i4);
    const float4 c1 = *reinterpret_cast<const float4*>(b + PLANE + i4);
    uintx4 o;
    o.x = pack2(c0.x, c1.x);
    o.y = pack2(c0.y, c1.y);
    o.z = pack2(c0.z, c1.z);
    o.w = pack2(c0.w, c1.w);
    tbl[t] = o;
}

__device__ __forceinline__ unsigned sel4(uintx4 q, unsigned o) {
    const unsigned a = (o & 1u) ? q.y : q.x;
    const unsigned b = (o & 1u) ? q.w : q.z;
    return (o & 2u) ? b : a;
}

// ---- level-clustered fused gather ----
__global__ __launch_bounds__(256) void grid_gather_kernel(
    const unsigned* __restrict__ tbl,
    const float* __restrict__ inputs,
    floatx2* __restrict__ out)
{
    const int t = blockIdx.x * 256 + threadIdx.x;

    float x0[PPT], y0[PPT], z0[PPT];
#pragma unroll
    for (int p = 0; p < PPT; ++p) {
        const int i = t + p * TTHREADS;
        const float x = __builtin_nontemporal_load(&inputs[3 * i + 0]);
        const float y = __builtin_nontemporal_load(&inputs[3 * i + 1]);
        const float z = __builtin_nontemporal_load(&inputs[3 * i + 2]);
        x0[p] = (x + 1.0f) * 0.5f;
        y0[p] = (y + 1.0f) * 0.5f;
        z0[p] = (z + 1.0f) * 0.5f;
    }

    float o0[PPT], o1[PPT];
#pragma unroll
    for (int p = 0; p < PPT; ++p) { o0[p] = 0.0f; o1[p] = 0.0f; }

#pragma unroll
    for (int level = 0; level < 3; ++level) {
        const float scale = (float)((128 << level) - 1);  // 127, 255, 511
        const unsigned lvl = (unsigned)level << 19;

#pragma unroll
        for (int p = 0; p < PPT; ++p) {
            const float px = fmaf(x0[p], scale, 0.5f);
            const float py = fmaf(y0[p], scale, 0.5f);
            const float pz = fmaf(z0[p], scale, 0.5f);
            const float fx = floorf(px), fy = floorf(py), fz = floorf(pz);
            const float rx = px - fx, ry = py - fy, rz = pz - fz;
            const unsigned gx = (unsigned)fx, gy = (unsigned)fy, gz = (unsigned)fz;

            const unsigned d = gx ^ (gx + 1u);            // 1,3,7,15,...
            const unsigned hy0 = gy * 2654435761u;
            const unsigned hy1 = (gy + 1u) * 2654435761u;
            const unsigned hz0 = gz * 805459861u;
            const unsigned hz1 = (gz + 1u) * 805459861u;

            unsigned P0[4];
            P0[0] = lvl | ((gx ^ hy0 ^ hz0) & HMASK);
            P0[1] = lvl | ((gx ^ hy1 ^ hz0) & HMASK);
            P0[2] = lvl | ((gx ^ hy0 ^ hz1) & HMASK);
            P0[3] = lvl | ((gx ^ hy1 ^ hz1) & HMASK);

            unsigned e0[4], e1[4];
            if (d == 1u) {
                // partner adjacent within aligned 8B (p = 1/2)
#pragma unroll
                for (int j = 0; j < 4; ++j) {
                    const unsigned P = P0[j];
                    const uintx2 q = *reinterpret_cast<const uintx2*>(tbl + (P & ~1u));
                    const unsigned o = P & 1u;
                    e0[j] = o ? q.y : q.x;
                    e1[j] = o ? q.x : q.y;
                }
            } else if (d == 3u) {
                // partner within aligned 16B quad (p = 1/4)
#pragma unroll
                for (int j = 0; j < 4; ++j) {
                    const unsigned P = P0[j];
                    const uintx4 q = *reinterpret_cast<const uintx4*>(tbl + (P & ~3u));
                    const unsigned o = P & 3u;
                    e0[j] = sel4(q, o);
                    e1[j] = sel4(q, o ^ 3u);
                }
            } else {
                // distant partner: two scalar 4B loads (p = 1/4)
#pragma unroll
                for (int j = 0; j < 4; ++j) {
                    const unsigned P = P0[j];
                    e0[j] = tbl[P];
                    e1[j] = tbl[P ^ d];
                }
            }

            const float wx1 = rx, wx0 = 1.0f - rx;
            const float wy1 = ry, wy0 = 1.0f - ry;
            const float wz1 = rz, wz0 = 1.0f - rz;
            const float wyz[4] = { wy0 * wz0, wy1 * wz0, wy0 * wz1, wy1 * wz1 };
#pragma unroll
            for (int j = 0; j < 4; ++j) {
                const __half2 a = *reinterpret_cast<const __half2*>(&e0[j]);
                const __half2 b = *reinterpret_cast<const __half2*>(&e1[j]);
                const float2 fa = __half22float2(a);
                const float2 fb = __half22float2(b);
                const float wA = wx0 * wyz[j], wB = wx1 * wyz[j];
                o0[p] = fmaf(wA, fa.x, o0[p]); o1[p] = fmaf(wA, fa.y, o1[p]);
                o0[p] = fmaf(wB, fb.x, o0[p]); o1[p] = fmaf(wB, fb.y, o1[p]);
            }
        }
        // phase alignment: keep all resident waves on the same level so the
        // active table working set stays at one 2 MB level (L2-resident)
        __syncthreads();
    }

#pragma unroll
    for (int p = 0; p < PPT; ++p) {
        floatx2 r; r.x = o0[p]; r.y = o1[p];
        __builtin_nontemporal_store(r, &out[t + p * TTHREADS]);
    }
}

// ---- fallback (R1 kernel) if ws_size is too small for the packed table ----
__global__ __launch_bounds__(256) void grid_fallback_kernel(
    const float* __restrict__ triplane,
    const float* __restrict__ inputs,
    float* __restrict__ out)
{
    const int i = blockIdx.x * blockDim.x + threadIdx.x;
    if (i >= NPOINTS) return;
    const float x0 = (inputs[3 * i + 0] + 1.0f) * 0.5f;
    const float y0 = (inputs[3 * i + 1] + 1.0f) * 0.5f;
    const float z0 = (inputs[3 * i + 2] + 1.0f) * 0.5f;
    float o0 = 0.0f, o1 = 0.0f;
#pragma unroll
    for (int level = 0; level < 3; ++level) {
        const float scale = (float)((128 << level) - 1);
        const float px = fmaf(x0, scale, 0.5f);
        const float py = fmaf(y0, scale, 0.5f);
        const float pz = fmaf(z0, scale, 0.5f);
        const float fx = floorf(px), fy = floorf(py), fz = floorf(pz);
        const float rx = px - fx, ry = py - fy, rz = pz - fz;
        const unsigned gx = (unsigned)fx, gy = (unsigned)fy, gz = (unsigned)fz;
        const float* __restrict__ base = triplane + level * (2 * PLANE);
#pragma unroll
        for (int c = 0; c < 8; ++c) {
            const unsigned bx = (c >> 0) & 1, by = (c >> 1) & 1, bz = (c >> 2) & 1;
            const unsigned h = (gx + bx) ^ ((gy + by) * 2654435761u) ^ ((gz + bz) * 805459861u);
            const unsigned local = h & HMASK;
            const float w = (bx ? rx : 1.0f - rx) * (by ? ry : 1.0f - ry) * (bz ? rz : 1.0f - rz);
            o0 = fmaf(w, base[local], o0);
            o1 = fmaf(w, base[PLANE + local], o1);
        }
    }
    reinterpret_cast<float2*>(out)[i] = make_float2(o0, o1);
}

extern "C" void kernel_launch(void* const* d_in, const int* in_sizes, int n_in,
                              void* d_out, int out_size, void* d_ws, size_t ws_size,
                              hipStream_t stream) {
    const float* triplane = (const float*)d_in[0];  // 3*2*1024*512 fp32
    const float* inputs   = (const float*)d_in[1];  // B*3 fp32
    const int threads = 256;

    if (ws_size >= (size_t)NTAB * sizeof(unsigned)) {
        unsigned* tbl = (unsigned*)d_ws;
        tp_convert_kernel<<<(NTAB / 4) / threads, threads, 0, stream>>>(
            triplane, (uintx4*)tbl);
        grid_gather_kernel<<<GBLOCKS, threads, 0, stream>>>(tbl, inputs, (floatx2*)d_out);
    } else {
        grid_fallback_kernel<<<NPOINTS / threads, threads, 0, stream>>>(
            triplane, inputs, (float*)d_out);
    }
}